// Round 9
// baseline (436.077 us; speedup 1.0000x reference)
//
#include <hip/hip_runtime.h>
#include <hip/hip_bf16.h>

// ---- problem constants ----
#define SEQ   4096
#define DMODEL 2048
#define NHEAD 16
#define NKVH  4
#define HDIM  128
#define NQ    (NHEAD*HDIM)   // 2048
#define NKV   (NKVH*HDIM)    // 512
#define NQKV  (NQ + 2*NKV)   // 3072
#define SCALE 0.08838834764831845f
#define LOG2E 1.4426950408889634f
#define SCL2  (SCALE * LOG2E)

typedef __bf16 bf16x4 __attribute__((ext_vector_type(4)));
typedef __bf16 bf16x8 __attribute__((ext_vector_type(8)));
typedef float  f32x4  __attribute__((ext_vector_type(4)));

#define GLOBAL_CPTR(x) ((const __attribute__((address_space(1))) void*)(x))
#define LDS_PTR(x)     ((__attribute__((address_space(3))) void*)(x))

// ---------------------------------------------------------------------------
// Fused fp32 -> bf16 convert for all 5 regions (4 weights + hidden) in ONE
// launch. Region boundaries are exact multiples of 256 blocks.
// Blocks: [0,2048) wq -> wqkv; [2048,2560) wk; [2560,3072) wv;
//         [3072,5120) wo -> wo_b; [5120,9216) hidden -> hbuf.
// ---------------------------------------------------------------------------
__global__ __launch_bounds__(256)
void convert_all(__bf16* __restrict__ wqkv, __bf16* __restrict__ wob,
                 __bf16* __restrict__ hb,
                 const float* __restrict__ wq, const float* __restrict__ wk,
                 const float* __restrict__ wv, const float* __restrict__ wo,
                 const float* __restrict__ hid)
{
    const int b = blockIdx.x;
    const float* src;
    __bf16* dst;
    int ib;
    if (b < 2048)      { src = wq;  dst = wqkv;                                 ib = b; }
    else if (b < 2560) { src = wk;  dst = wqkv + (size_t)NQ * DMODEL;           ib = b - 2048; }
    else if (b < 3072) { src = wv;  dst = wqkv + (size_t)(NQ + NKV) * DMODEL;   ib = b - 2560; }
    else if (b < 5120) { src = wo;  dst = wob;                                  ib = b - 3072; }
    else               { src = hid; dst = hb;                                   ib = b - 5120; }
    const size_t e0 = ((size_t)ib * 256 + threadIdx.x) * 8;
    const float4 a = *(const float4*)(src + e0);
    const float4 c = *(const float4*)(src + e0 + 4);
    bf16x8 o;
    o[0]=(__bf16)a.x; o[1]=(__bf16)a.y; o[2]=(__bf16)a.z; o[3]=(__bf16)a.w;
    o[4]=(__bf16)c.x; o[5]=(__bf16)c.y; o[6]=(__bf16)c.z; o[7]=(__bf16)c.w;
    *(bf16x8*)(dst + e0) = o;
}

// ---------------------------------------------------------------------------
// GEMM: C = A[M][K](bf16) * W[N][K]^T(bf16), fp32 accumulate, glds staging.
// Round-8 structure (measured-good): dbuf stage-ahead + fragment-read bank
// swizzle (glds dest linear, SOURCE slot ^= (row>>1)&3, READ quad ^=
// (l16>>1)&3). Per K-step: barrier -> issue STAGE(k+1, buf^1) -> compute.
// cmode 1: fp32 C[M][N]. cmode 3: fused QKV + RoPE router
// (q -> Cv roped, k -> kb2 roped, v -> vt2 transposed).
// ---------------------------------------------------------------------------
__global__ __launch_bounds__(256)
void gemm_bt(const __bf16* __restrict__ A, const __bf16* __restrict__ Bw,
             void* __restrict__ Cv, __bf16* __restrict__ kb2, __bf16* __restrict__ vt2,
             const float* __restrict__ ct, const float* __restrict__ st,
             int M, int N, int K, int cmode)
{
    __shared__ alignas(16) __bf16 As[2][128*32];
    __shared__ alignas(16) __bf16 Bs[2][128*32];

    const int tid  = threadIdx.x;
    const int w    = tid >> 6;
    const int lane = tid & 63;
    const int l16  = lane & 15;
    const int quad = lane >> 4;
    const int m0 = blockIdx.y * 128;
    const int n0 = blockIdx.x * 128;

    const int srow = lane >> 2;        // glds: 0..15
    const int scol = (((lane & 3) ^ ((lane >> 3) & 3)) * 8);
    const int rsw  = (quad ^ ((l16 >> 1) & 3)) * 8;

    const int wm = (w >> 1) * 64;
    int coff[4];
    #pragma unroll
    for (int nt = 0; nt < 4; ++nt)
        coff[nt] = (cmode == 3) ? ((w & 1) * 32 + ((nt & 2) ? 64 : 0) + (nt & 1) * 16)
                                : ((w & 1) * 64 + nt * 16);

    f32x4 acc[4][4];
    #pragma unroll
    for (int mt = 0; mt < 4; ++mt)
        #pragma unroll
        for (int nt = 0; nt < 4; ++nt)
            acc[mt][nt] = (f32x4){0.f, 0.f, 0.f, 0.f};

    auto STAGE = [&](int k0, int b) {
        #pragma unroll
        for (int c = 0; c < 2; ++c) {
            const int r0 = w * 32 + c * 16;
            const __bf16* ga = A + (size_t)(m0 + r0 + srow) * K + k0 + scol;
            __builtin_amdgcn_global_load_lds(GLOBAL_CPTR(ga), LDS_PTR(&As[b][r0 * 32]), 16, 0, 0);
            const __bf16* gb = Bw + (size_t)(n0 + r0 + srow) * K + k0 + scol;
            __builtin_amdgcn_global_load_lds(GLOBAL_CPTR(gb), LDS_PTR(&Bs[b][r0 * 32]), 16, 0, 0);
        }
    };

    STAGE(0, 0);
    for (int k0 = 0; k0 < K; k0 += 32) {
        const int b = (k0 >> 5) & 1;
        __syncthreads();               // stage(k0) visible; reads of buf b^1 done
        if (k0 + 32 < K) STAGE(k0 + 32, b ^ 1);

        bf16x8 af[4], bf[4];
        #pragma unroll
        for (int mt = 0; mt < 4; ++mt)
            af[mt] = *(const bf16x8*)&As[b][(wm + mt*16 + l16) * 32 + rsw];
        #pragma unroll
        for (int nt = 0; nt < 4; ++nt)
            bf[nt] = *(const bf16x8*)&Bs[b][(coff[nt] + l16) * 32 + rsw];
        __builtin_amdgcn_s_setprio(1);
        #pragma unroll
        for (int mt = 0; mt < 4; ++mt)
            #pragma unroll
            for (int nt = 0; nt < 4; ++nt)
                acc[mt][nt] = __builtin_amdgcn_mfma_f32_16x16x32_bf16(
                    af[mt], bf[nt], acc[mt][nt], 0, 0, 0);
        __builtin_amdgcn_s_setprio(0);
    }

    // epilogue: C/D layout col=lane&15, row=quad*4+r
    if (cmode == 3) {
        if (n0 >= 2560) {
            #pragma unroll
            for (int mt = 0; mt < 4; ++mt)
                #pragma unroll
                for (int nt = 0; nt < 4; ++nt) {
                    const int col = (n0 - 2560) + coff[nt] + l16;   // 0..511
                    const int row = m0 + wm + mt*16 + quad*4;
                    bf16x4 pk;
                    #pragma unroll
                    for (int r = 0; r < 4; ++r) pk[r] = (__bf16)acc[mt][nt][r];
                    *(bf16x4*)&vt2[(size_t)col * M + row] = pk;
                }
        } else {
            __bf16* dst;
            int ncols, cb;
            if (n0 < 2048) { dst = (__bf16*)Cv; ncols = NQ;  cb = n0; }
            else           { dst = kb2;         ncols = NKV; cb = n0 - 2048; }
            #pragma unroll
            for (int mt = 0; mt < 4; ++mt)
                #pragma unroll
                for (int np = 0; np < 2; ++np) {
                    const int d = coff[np] + l16;     // 0..63 (head-local low half)
                    #pragma unroll
                    for (int r = 0; r < 4; ++r) {
                        const int s = m0 + wm + mt*16 + quad*4 + r;
                        const float c  = ct[s * HDIM + d];
                        const float sn = st[s * HDIM + d];
                        const float x1 = acc[mt][np][r];
                        const float x2 = acc[mt][np + 2][r];
                        dst[(size_t)s * ncols + cb + d]      = (__bf16)(x1 * c - x2 * sn);
                        dst[(size_t)s * ncols + cb + d + 64] = (__bf16)(x2 * c + x1 * sn);
                    }
                }
        }
    } else {
        float* Cf = (float*)Cv;
        #pragma unroll
        for (int mt = 0; mt < 4; ++mt)
            #pragma unroll
            for (int nt = 0; nt < 4; ++nt) {
                const int row = m0 + wm + mt*16 + quad*4;
                const int col = n0 + coff[nt] + l16;
                #pragma unroll
                for (int r = 0; r < 4; ++r)
                    Cf[(size_t)(row + r) * N + col] = acc[mt][nt][r];
            }
    }
}

// ---------------------------------------------------------------------------
// Flash attention, causal, GQA — round 9: 2x arithmetic intensity per DS op.
// Diagnosis: attn is LDS-issue-bound (34 ds_read_b128 x ~12cyc + 16 Ps writes
// per wave-tile ~= 500 DS cyc vs ~165 MFMA cyc -> MfmaUtil 22%, matches).
// Fix: 4 waves x 32 q-rows (two mt sub-tiles) instead of 8 waves x 16 rows.
// Every K/V fragment read now feeds 2 MFMAs -> DS per unit work ~1.6x lower.
// Same 128-row block, same grid (32,16) + complementary qt pairing (load
// balance preserved). Round-2's version of this spilled at a 170-VGPR cap
// (LB(256,3)); here LB(256,2) caps at 256 for a ~190 peak. LDS 80KB ->
// 2 blocks/CU (8 waves/CU). Stage-ahead dbuf unchanged; wave stages kc=w of
// K and (c2=w&1, dim-half=w>>1) of V (8 glds/wave/tile).
// All LDS swizzles carried over (involutions key off row bits invariant to
// the mt*16 offset). Included tiles always have n0g <= wrow (both multiples
// of 32/64) -> no fully-masked sub-tile; per-mt uniform mask branch.
// Row-sums via ones-MFMA per mt. No-max softmax. O in-place over Q.
// ---------------------------------------------------------------------------
__global__ __launch_bounds__(256, 2)
void attn_kernel(__bf16* __restrict__ QO, const __bf16* __restrict__ Kb,
                 const __bf16* __restrict__ Vt)
{
    __shared__ alignas(16) __bf16 Klds[2][4][64][32];   // [buf][kc][key][dim%32]
    __shared__ alignas(16) __bf16 Vlds[2][2][128][32];  // [buf][c2][dim][seq%32]
    __shared__ alignas(16) __bf16 Ps[4][32][64];        // [wave][qrow 0..31], XOR-swizzled

    const int tid  = threadIdx.x;
    const int w    = tid >> 6;          // 0..3
    const int lane = tid & 63;
    const int l16  = lane & 15;
    const int quad = lane >> 4;
    const int bx = (int)blockIdx.x;
    const int h  = (int)blockIdx.y;
    const int g  = h >> 2;
    const int nbx = (int)gridDim.x;     // 32
    const int qt = (h < 8) ? (nbx - 1 - bx) : bx;   // complementary pairing
    const int m0 = qt * 128;
    const int wrow = m0 + w * 32;       // this wave's first q-row (32 rows)

    const int srow = lane >> 2;
    const int scol = (((lane & 3) ^ ((lane >> 3) & 3)) * 8);
    const int rsw  = (quad ^ ((l16 >> 1) & 3)) * 8;

    // Q A-frags: row = wrow + mt*16 + l16, k = kc*32 + quad*8 + j
    bf16x8 qf[2][4];
    #pragma unroll
    for (int mt = 0; mt < 2; ++mt) {
        const size_t qbase = (size_t)(wrow + mt * 16 + l16) * NQ + h * HDIM;
        #pragma unroll
        for (int kc = 0; kc < 4; ++kc)
            qf[mt][kc] = *(const bf16x8*)&QO[qbase + kc * 32 + quad * 8];
    }

    bf16x8 onesf;
    #pragma unroll
    for (int i = 0; i < 8; ++i) onesf[i] = (__bf16)1.0f;

    // staging: wave w owns K dim-chunk kc=w and V (seq-half w&1, dim-half w>>1)
    const __bf16* kSrc = Kb + (size_t)srow * NKV + g * HDIM + w * 32 + scol;
    const __bf16* vSrc = Vt + (size_t)(g * HDIM + (w >> 1) * 64 + srow) * SEQ + (w & 1) * 32 + scol;

    auto STAGE = [&](int jj, int b) {
        const int n0g = jj * 64;
        #pragma unroll
        for (int c = 0; c < 4; ++c) {
            __builtin_amdgcn_global_load_lds(
                GLOBAL_CPTR(kSrc + (size_t)(n0g + c * 16) * NKV),
                LDS_PTR(&Klds[b][w][c * 16][0]), 16, 0, 0);
            __builtin_amdgcn_global_load_lds(
                GLOBAL_CPTR(vSrc + (size_t)(c * 16) * SEQ + n0g),
                LDS_PTR(&Vlds[b][w & 1][(w >> 1) * 64 + c * 16][0]), 16, 0, 0);
        }
    };

    f32x4 lacc[2];
    f32x4 oacc[2][8];
    #pragma unroll
    for (int mt = 0; mt < 2; ++mt) {
        lacc[mt] = (f32x4){0.f, 0.f, 0.f, 0.f};
        #pragma unroll
        for (int t = 0; t < 8; ++t) oacc[mt][t] = (f32x4){0.f, 0.f, 0.f, 0.f};
    }

    const int njt = 2 * qt + 2;         // 64-key tiles under causal reach
    STAGE(0, 0);
    for (int j = 0; j < njt; ++j) {
        __syncthreads();                // stage(j) visible; reads of buf (j+1)&1 done
        if (j + 1 < njt) STAGE(j + 1, (j + 1) & 1);
        const int n0g = j * 64;
        if (n0g > wrow + 31) continue;  // wave-uniform causal skip
        const int b = j & 1;

        // S strips (both mt) = Q(32x128) * K^T(128x64); kf shared across mt
        f32x4 sacc[2][4];
        #pragma unroll
        for (int mt = 0; mt < 2; ++mt)
            #pragma unroll
            for (int nt = 0; nt < 4; ++nt) sacc[mt][nt] = (f32x4){0.f, 0.f, 0.f, 0.f};
        __builtin_amdgcn_s_setprio(1);
        #pragma unroll
        for (int kc = 0; kc < 4; ++kc) {
            #pragma unroll
            for (int nt = 0; nt < 4; ++nt) {
                const bf16x8 kf = *(const bf16x8*)&Klds[b][kc][nt * 16 + l16][rsw];
                sacc[0][nt] = __builtin_amdgcn_mfma_f32_16x16x32_bf16(qf[0][kc], kf, sacc[0][nt], 0, 0, 0);
                sacc[1][nt] = __builtin_amdgcn_mfma_f32_16x16x32_bf16(qf[1][kc], kf, sacc[1][nt], 0, 0, 0);
            }
        }
        __builtin_amdgcn_s_setprio(0);

        // no-max softmax per mt; mask only on diagonal-overlap tiles
        #pragma unroll
        for (int mt = 0; mt < 2; ++mt) {
            const int rowbase = wrow + mt * 16;
            if (n0g + 64 > rowbase) {
                #pragma unroll
                for (int r = 0; r < 4; ++r) {
                    const int qr = rowbase + quad * 4 + r;
                    const int prow = mt * 16 + quad * 4 + r;
                    const int pxor = (prow & 7) << 3;
                    #pragma unroll
                    for (int nt = 0; nt < 4; ++nt) {
                        float e = exp2f(sacc[mt][nt][r] * SCL2);
                        if ((n0g + nt * 16 + l16) > qr) e = 0.f;
                        Ps[w][prow][(nt * 16 + l16) ^ pxor] = (__bf16)e;
                    }
                }
            } else {
                #pragma unroll
                for (int r = 0; r < 4; ++r) {
                    const int prow = mt * 16 + quad * 4 + r;
                    const int pxor = (prow & 7) << 3;
                    #pragma unroll
                    for (int nt = 0; nt < 4; ++nt)
                        Ps[w][prow][(nt * 16 + l16) ^ pxor] = (__bf16)exp2f(sacc[mt][nt][r] * SCL2);
                }
            }
        }

        // P fragments (wave-private roundtrip): row-sums + O += P*V; vf shared
        bf16x8 pa[2][2];
        #pragma unroll
        for (int mt = 0; mt < 2; ++mt)
            #pragma unroll
            for (int kc = 0; kc < 2; ++kc)
                pa[mt][kc] = *(const bf16x8*)&Ps[w][mt * 16 + l16][(kc * 32 + quad * 8) ^ ((l16 & 7) << 3)];

        __builtin_amdgcn_s_setprio(1);
        #pragma unroll
        for (int mt = 0; mt < 2; ++mt) {
            lacc[mt] = __builtin_amdgcn_mfma_f32_16x16x32_bf16(pa[mt][0], onesf, lacc[mt], 0, 0, 0);
            lacc[mt] = __builtin_amdgcn_mfma_f32_16x16x32_bf16(pa[mt][1], onesf, lacc[mt], 0, 0, 0);
        }
        #pragma unroll
        for (int kc = 0; kc < 2; ++kc)
            #pragma unroll
            for (int t = 0; t < 8; ++t) {
                const bf16x8 vf = *(const bf16x8*)&Vlds[b][kc][t * 16 + l16][rsw];
                oacc[0][t] = __builtin_amdgcn_mfma_f32_16x16x32_bf16(pa[0][kc], vf, oacc[0][t], 0, 0, 0);
                oacc[1][t] = __builtin_amdgcn_mfma_f32_16x16x32_bf16(pa[1][kc], vf, oacc[1][t], 0, 0, 0);
            }
        __builtin_amdgcn_s_setprio(0);
    }

    // epilogue: O in-place over Q (this block's own slice)
    #pragma unroll
    for (int mt = 0; mt < 2; ++mt) {
        float rinv[4];
        #pragma unroll
        for (int r = 0; r < 4; ++r) rinv[r] = 1.f / lacc[mt][r];
        #pragma unroll
        for (int t = 0; t < 8; ++t)
            #pragma unroll
            for (int r = 0; r < 4; ++r) {
                const int qr = wrow + mt * 16 + quad * 4 + r;
                QO[(size_t)qr * NQ + h * HDIM + t * 16 + l16] = (__bf16)(oacc[mt][t][r] * rinv[r]);
            }
    }
}

// ---------------------------------------------------------------------------
extern "C" void kernel_launch(void* const* d_in, const int* in_sizes, int n_in,
                              void* d_out, int out_size, void* d_ws, size_t ws_size,
                              hipStream_t stream)
{
    const float* hidden = (const float*)d_in[0];
    const float* cosp   = (const float*)d_in[1];
    const float* sinp   = (const float*)d_in[2];
    // d_in[3] = attention_mask: exactly causal -> handled analytically
    const float* wq = (const float*)d_in[4];
    const float* wk = (const float*)d_in[5];
    const float* wv = (const float*)d_in[6];
    const float* wo = (const float*)d_in[7];

    const size_t nw_q = (size_t)NQ  * DMODEL;   // 4.19M
    const size_t nw_k = (size_t)NKV * DMODEL;   // 1.05M
    const size_t nq_e = (size_t)SEQ * NQ;       // 8.39M
    const size_t nk_e = (size_t)SEQ * NKV;      // 2.10M

    __bf16* ws     = (__bf16*)d_ws;             // total 46.1 MB (proven available)
    __bf16* wo_b   = ws;
    __bf16* wqkv_b = wo_b + nw_q;               // [3072][2048]: q rows 0-2047, k 2048-2559, v 2560-3071
    __bf16* qbuf   = wqkv_b + nw_q + 2 * nw_k;  // [4096][2048]; O written in-place
    __bf16* kbuf   = qbuf + nq_e;               // [4096][512]
    __bf16* vtb    = kbuf + nk_e;               // [512][4096] (written transposed)
    __bf16* hbuf   = (__bf16*)d_out;            // bf16 hidden scratch (16.8 MB of the
                                                // 33.5 MB output; dead until final GEMM)

    // one fused convert launch: wq|wk|wv -> wqkv_b, wo -> wo_b, hidden -> hbuf
    convert_all<<<dim3(9216), dim3(256), 0, stream>>>(
        wqkv_b, wo_b, hbuf, wq, wk, wv, wo, hidden);

    // fused QKV projection + RoPE (k/q) + V-transpose
    gemm_bt<<<dim3(NQKV / 128, SEQ / 128), dim3(256), 0, stream>>>(
        hbuf, wqkv_b, qbuf, kbuf, vtb, cosp, sinp, SEQ, NQKV, DMODEL, 3);

    attn_kernel<<<dim3(SEQ / 128, NHEAD), dim3(256), 0, stream>>>(qbuf, kbuf, vtb);

    // output projection (fp32 out)
    gemm_bt<<<dim3(DMODEL / 128, SEQ / 128), dim3(256), 0, stream>>>(
        qbuf, wo_b, d_out, nullptr, nullptr, nullptr, nullptr, SEQ, DMODEL, DMODEL, 1);
}